// Round 13
// baseline (688.593 us; speedup 1.0000x reference)
//
#include <hip/hip_runtime.h>

#define HC 256      // HEADS*HID
#define HEADS 8
#define HID 32
#define GRAPHS 512
#define NEG_SLOPE 0.2f

typedef __bf16 bf16x8 __attribute__((ext_vector_type(8)));
typedef float f32x4 __attribute__((ext_vector_type(4)));

// ------------------------------------------------------------------
// bf16 helpers (round-to-nearest-even)
__device__ __forceinline__ unsigned short f2bf(float x) {
    unsigned u = __float_as_uint(x);
    return (unsigned short)((u + 0x7fffu + ((u >> 16) & 1u)) >> 16);
}
__device__ __forceinline__ float bf2f(unsigned short b) {
    return __uint_as_float(((unsigned)b) << 16);
}

// int32/int64 index handling (JAX may emit either for edge_index/batch)
__device__ __forceinline__ int IDX(const void* p, long long i, int mode) {
    if (mode) return (int)((const long long*)p)[i];
    return ((const int*)p)[i];
}

__global__ void detect_kernel(const unsigned int* __restrict__ words, int* __restrict__ mode, int e) {
    __shared__ unsigned int red[256];
    unsigned int v = 0;
    int lim = e < 4096 ? e : 4096;
    for (int i = threadIdx.x; i < lim; i += 256) v |= words[2 * i + 1];
    red[threadIdx.x] = v;
    __syncthreads();
    for (int off = 128; off > 0; off >>= 1) {
        if (threadIdx.x < off) red[threadIdx.x] |= red[threadIdx.x + off];
        __syncthreads();
    }
    if (threadIdx.x == 0) *mode = (red[0] == 0u) ? 1 : 0;  // 1 => int64
}

// ------------------------------------------------------------------
// CSR build: histogram -> scan -> scatter
__global__ void hist_kernel(const void* __restrict__ edge, const int* __restrict__ mode,
                            int* __restrict__ hist, int e) {
    int m = mode[0];
    int i = blockIdx.x * blockDim.x + threadIdx.x;
    if (i < e) atomicAdd(&hist[IDX(edge, (long long)e + i, m)], 1);
}

__global__ void scan1(const int* __restrict__ hist, int* __restrict__ excl,
                      int* __restrict__ bsum, int n) {
    __shared__ int buf[256];
    int i = blockIdx.x * 256 + threadIdx.x;
    int v = (i < n) ? hist[i] : 0;
    buf[threadIdx.x] = v;
    __syncthreads();
    for (int off = 1; off < 256; off <<= 1) {
        int t = (threadIdx.x >= (unsigned)off) ? buf[threadIdx.x - off] : 0;
        __syncthreads();
        buf[threadIdx.x] += t;
        __syncthreads();
    }
    if (i < n) excl[i] = buf[threadIdx.x] - v;
    if (threadIdx.x == 255) bsum[blockIdx.x] = buf[255];
}

__global__ void scan2(int* __restrict__ bsum, int nb) {
    __shared__ int buf[256];
    int v = (threadIdx.x < (unsigned)nb) ? bsum[threadIdx.x] : 0;
    buf[threadIdx.x] = v;
    __syncthreads();
    for (int off = 1; off < 256; off <<= 1) {
        int t = (threadIdx.x >= (unsigned)off) ? buf[threadIdx.x - off] : 0;
        __syncthreads();
        buf[threadIdx.x] += t;
        __syncthreads();
    }
    if (threadIdx.x < (unsigned)nb) bsum[threadIdx.x] = buf[threadIdx.x] - v;  // exclusive
}

__global__ void scan3(int* __restrict__ row_ptr, const int* __restrict__ bsum, int n, int e) {
    int i = blockIdx.x * 256 + threadIdx.x;
    if (i < n) row_ptr[i] += bsum[i >> 8];
    if (i == 0) row_ptr[n] = e;
}

__global__ void scatter_kernel(const void* __restrict__ edge, const int* __restrict__ mode,
                               const int* __restrict__ row_ptr, int* __restrict__ fill,
                               int* __restrict__ outs, int* __restrict__ outd, int e) {
    int m = mode[0];
    int i = blockIdx.x * blockDim.x + threadIdx.x;
    if (i < e) {
        int d = IDX(edge, (long long)e + i, m);
        int pos = row_ptr[d] + atomicAdd(&fill[d], 1);
        outs[pos] = IDX(edge, (long long)i, m);
        outd[pos] = d;
    }
}

// ------------------------------------------------------------------
// degree bucket-sort of nodes (once): nodes sorted by degree so wave partners
// have matching degree -> no divergence waste in the aggregate edge loop.
__global__ void deghist_kernel(const int* __restrict__ row_ptr, int* __restrict__ dhist, int n) {
    int i = blockIdx.x * blockDim.x + threadIdx.x;
    if (i < n) {
        int d = row_ptr[i + 1] - row_ptr[i];
        d = d > 255 ? 255 : d;
        atomicAdd(&dhist[d], 1);
    }
}

__global__ void dscan_kernel(int* __restrict__ dhist) {   // 256-bin exclusive scan, 1 block
    __shared__ int buf[256];
    int v = dhist[threadIdx.x];
    buf[threadIdx.x] = v;
    __syncthreads();
    for (int off = 1; off < 256; off <<= 1) {
        int t = (threadIdx.x >= (unsigned)off) ? buf[threadIdx.x - off] : 0;
        __syncthreads();
        buf[threadIdx.x] += t;
        __syncthreads();
    }
    dhist[threadIdx.x] = buf[threadIdx.x] - v;
}

__global__ void degscatter_kernel(const int* __restrict__ row_ptr, const int* __restrict__ dbase,
                                  int* __restrict__ dfill, int* __restrict__ nodeperm, int n) {
    int i = blockIdx.x * blockDim.x + threadIdx.x;
    if (i < n) {
        int d = row_ptr[i + 1] - row_ptr[i];
        d = d > 255 ? 255 : d;
        int pos = dbase[d] + atomicAdd(&dfill[d], 1);
        nodeperm[pos] = i;
    }
}

// ------------------------------------------------------------------
// x fp32 -> bf16 cast (vectorized)
__global__ void cast_kernel(const float* __restrict__ x, unsigned short* __restrict__ xb,
                            int nquad) {
    int i = blockIdx.x * blockDim.x + threadIdx.x;
    if (i >= nquad) return;
    float4 v = *(const float4*)(x + (size_t)i * 4);
    ushort4 u = {f2bf(v.x), f2bf(v.y), f2bf(v.z), f2bf(v.w)};
    *(ushort4*)(xb + (size_t)i * 4) = u;
}

// W fp32 [K][256] -> Wt bf16 [256][K]
__global__ void wtrans_kernel(const float* __restrict__ W, unsigned short* __restrict__ Wt,
                              int K) {
    int idx = blockIdx.x * blockDim.x + threadIdx.x;
    if (idx >= 256 * K) return;
    int c = idx / K, k = idx - c * K;
    Wt[idx] = f2bf(W[(size_t)k * 256 + c]);
}

// ------------------------------------------------------------------
// bf16 MFMA GEMM with FUSED alpha epilogue.
__global__ __launch_bounds__(256) void gemm_mfma(const unsigned short* __restrict__ A,
                                                 const unsigned short* __restrict__ Wt,
                                                 unsigned short* __restrict__ Cb,
                                                 const float* __restrict__ a_src,
                                                 const float* __restrict__ a_dst,
                                                 float* __restrict__ asrc,
                                                 float* __restrict__ adst,
                                                 int M, int K) {
    __shared__ unsigned short Ab[64][40];
    __shared__ unsigned short Bt[128][40];
    const int tid = threadIdx.x;
    const int wave = tid >> 6, lane = tid & 63;
    const int wr = wave >> 1, wc = wave & 1;
    const int row0 = blockIdx.x * 64, col0 = blockIdx.y * 128;
    const int r4 = tid >> 2, q = tid & 3;
    const int l15 = lane & 15, g8 = (lane >> 4) * 8;
    f32x4 acc[2][4] = {};

    for (int k0 = 0; k0 < K; k0 += 32) {
        int ar = row0 + r4;
        ar = ar < M ? ar : M - 1;
        *(uint4*)&Ab[r4][q * 8] = *(const uint4*)&A[(size_t)ar * K + k0 + q * 8];
#pragma unroll
        for (int h = 0; h < 2; ++h) {
            int br = r4 + h * 64;
            *(uint4*)&Bt[br][q * 8] = *(const uint4*)&Wt[(size_t)(col0 + br) * K + k0 + q * 8];
        }
        __syncthreads();
        bf16x8 af[2], bfr[4];
#pragma unroll
        for (int i = 0; i < 2; ++i) af[i] = *(const bf16x8*)&Ab[wr * 32 + i * 16 + l15][g8];
#pragma unroll
        for (int j = 0; j < 4; ++j) bfr[j] = *(const bf16x8*)&Bt[wc * 64 + j * 16 + l15][g8];
#pragma unroll
        for (int i = 0; i < 2; ++i)
#pragma unroll
            for (int j = 0; j < 4; ++j)
                acc[i][j] = __builtin_amdgcn_mfma_f32_16x16x32_bf16(af[i], bfr[j], acc[i][j],
                                                                    0, 0, 0);
        __syncthreads();
    }
    const int g = lane >> 4;
    const int colbase = col0 + wc * 64;
    const int headA = colbase >> 5, headB = headA + 1;
    const float asA0 = a_src[headA * 32 + l15], asA1 = a_src[headA * 32 + 16 + l15];
    const float asB0 = a_src[headB * 32 + l15], asB1 = a_src[headB * 32 + 16 + l15];
    const float adA0 = a_dst[headA * 32 + l15], adA1 = a_dst[headA * 32 + 16 + l15];
    const float adB0 = a_dst[headB * 32 + l15], adB1 = a_dst[headB * 32 + 16 + l15];
#pragma unroll
    for (int i = 0; i < 2; ++i) {
#pragma unroll
        for (int r = 0; r < 4; ++r) {
            int row = row0 + wr * 32 + i * 16 + g * 4 + r;
            float pa = acc[i][0][r] * asA0 + acc[i][1][r] * asA1;
            float pb = acc[i][2][r] * asB0 + acc[i][3][r] * asB1;
            float qa = acc[i][0][r] * adA0 + acc[i][1][r] * adA1;
            float qb = acc[i][2][r] * adB0 + acc[i][3][r] * adB1;
#pragma unroll
            for (int off = 1; off < 16; off <<= 1) {
                pa += __shfl_xor(pa, off, 64);
                pb += __shfl_xor(pb, off, 64);
                qa += __shfl_xor(qa, off, 64);
                qb += __shfl_xor(qb, off, 64);
            }
            if (row < M) {
                if (l15 == 0) {
                    asrc[row * 8 + headA] = pa;
                    asrc[row * 8 + headB] = pb;
                    adst[row * 8 + headA] = qa;
                    adst[row * 8 + headB] = qb;
                }
#pragma unroll
                for (int j = 0; j < 4; ++j) {
                    int col = colbase + j * 16 + l15;
                    Cb[(size_t)row * HC + col] = f2bf(acc[i][j][r]);
                }
            }
        }
    }
}

// ------------------------------------------------------------------
// per-edge exponentiated weights (no max-shift), CSR order, layout [E][8] bf16
__global__ void wexp_kernel(const int* __restrict__ srcs, const int* __restrict__ dsts,
                            const float* __restrict__ asrc, const float* __restrict__ adst,
                            unsigned short* __restrict__ wexp, int e) {
    int i = blockIdx.x * blockDim.x + threadIdx.x;
    if (i >= e) return;
    int s = srcs[i], d = dsts[i];
    float4 s0 = *(const float4*)(asrc + (size_t)s * 8);
    float4 s1 = *(const float4*)(asrc + (size_t)s * 8 + 4);
    float4 d0 = *(const float4*)(adst + (size_t)d * 8);
    float4 d1 = *(const float4*)(adst + (size_t)d * 8 + 4);
    float v[8] = {s0.x + d0.x, s0.y + d0.y, s0.z + d0.z, s0.w + d0.w,
                  s1.x + d1.x, s1.y + d1.y, s1.z + d1.z, s1.w + d1.w};
    ushort4 u0, u1;
#pragma unroll
    for (int q = 0; q < 8; ++q) {
        float t = v[q] > 0.f ? v[q] : NEG_SLOPE * v[q];
        v[q] = __expf(fminf(t, 75.f));
    }
    u0 = (ushort4){f2bf(v[0]), f2bf(v[1]), f2bf(v[2]), f2bf(v[3])};
    u1 = (ushort4){f2bf(v[4]), f2bf(v[5]), f2bf(v[6]), f2bf(v[7])};
    *(ushort4*)(wexp + (size_t)i * 8) = u0;
    *(ushort4*)(wexp + (size_t)i * 8 + 4) = u1;
}

// ------------------------------------------------------------------
// SINGLE-PASS aggregate over degree-sorted nodes (wave partners have equal
// degree -> no divergence waste). Stream bf16 wexp + gather rows (chain depth 1).
#define ACC_EDGE(gv, wv)                                                      \
    do {                                                                      \
        unsigned _u0 = gv.x, _u1 = gv.y, _u2 = gv.z, _u3 = gv.w;              \
        acc[0] = fmaf(wv, __uint_as_float(_u0 << 16), acc[0]);                \
        acc[1] = fmaf(wv, __uint_as_float(_u0 & 0xffff0000u), acc[1]);        \
        acc[2] = fmaf(wv, __uint_as_float(_u1 << 16), acc[2]);                \
        acc[3] = fmaf(wv, __uint_as_float(_u1 & 0xffff0000u), acc[3]);        \
        acc[4] = fmaf(wv, __uint_as_float(_u2 << 16), acc[4]);                \
        acc[5] = fmaf(wv, __uint_as_float(_u2 & 0xffff0000u), acc[5]);        \
        acc[6] = fmaf(wv, __uint_as_float(_u3 << 16), acc[6]);                \
        acc[7] = fmaf(wv, __uint_as_float(_u3 & 0xffff0000u), acc[7]);        \
    } while (0)

template <bool LAST>
__global__ __launch_bounds__(256) void gat_aggregate(
    const unsigned short* __restrict__ hb, const unsigned short* __restrict__ wexp,
    const float* __restrict__ asrc, const float* __restrict__ adst,
    const int* __restrict__ row_ptr, const int* __restrict__ srcs,
    const int* __restrict__ nodeperm,
    const float* __restrict__ bias, unsigned short* __restrict__ out16,
    const void* __restrict__ batch, const int* __restrict__ mode,
    const float* __restrict__ lin_w, float* __restrict__ gsum,
    float* __restrict__ gcnt, int n) {
    const int lane = threadIdx.x & 63;
    const int half = lane >> 5;
    const int l32 = lane & 31;
    int wid = (int)((blockIdx.x * blockDim.x + threadIdx.x) >> 6);
    int idx = wid * 2 + half;
    if (idx >= n) return;
    const int node = nodeperm[idx];       // degree-sorted order
    const int head = l32 >> 2;
    const int c0 = l32 * 8;
    const int beg = row_ptr[node], end = row_ptr[node + 1];

    // self-loop weight (fp32, exact)
    float e0 = asrc[node * 8 + head] + adst[node * 8 + head];
    e0 = e0 > 0.f ? e0 : NEG_SLOPE * e0;
    float w0 = __expf(fminf(e0, 75.f));
    float denom = w0;
    float acc[8] = {};
    {
        uint4 g = *(const uint4*)(hb + (size_t)node * HC + c0);
        ACC_EDGE(g, w0);
    }
    int j = beg;
    for (; j + 4 <= end; j += 4) {
        int s0 = srcs[j], s1 = srcs[j + 1], s2 = srcs[j + 2], s3 = srcs[j + 3];
        uint4 g0 = *(const uint4*)(hb + (size_t)s0 * HC + c0);
        uint4 g1 = *(const uint4*)(hb + (size_t)s1 * HC + c0);
        uint4 g2 = *(const uint4*)(hb + (size_t)s2 * HC + c0);
        uint4 g3 = *(const uint4*)(hb + (size_t)s3 * HC + c0);
        float x0 = bf2f(wexp[(size_t)(j + 0) * 8 + head]);
        float x1 = bf2f(wexp[(size_t)(j + 1) * 8 + head]);
        float x2 = bf2f(wexp[(size_t)(j + 2) * 8 + head]);
        float x3 = bf2f(wexp[(size_t)(j + 3) * 8 + head]);
        denom += x0 + x1 + x2 + x3;
        ACC_EDGE(g0, x0);
        ACC_EDGE(g1, x1);
        ACC_EDGE(g2, x2);
        ACC_EDGE(g3, x3);
    }
    for (; j < end; ++j) {
        int s = srcs[j];
        uint4 g = *(const uint4*)(hb + (size_t)s * HC + c0);
        float x = bf2f(wexp[(size_t)j * 8 + head]);
        denom += x;
        ACC_EDGE(g, x);
    }

    const float invd = 1.f / (denom + 1e-16f);
    float4 b0 = *(const float4*)(bias + c0);
    float4 b1 = *(const float4*)(bias + c0 + 4);
    float o[8] = {fmaf(acc[0], invd, b0.x), fmaf(acc[1], invd, b0.y),
                  fmaf(acc[2], invd, b0.z), fmaf(acc[3], invd, b0.w),
                  fmaf(acc[4], invd, b1.x), fmaf(acc[5], invd, b1.y),
                  fmaf(acc[6], invd, b1.z), fmaf(acc[7], invd, b1.w)};
#pragma unroll
    for (int q = 0; q < 8; ++q) o[q] = o[q] > 0.f ? o[q] : __expf(o[q]) - 1.f;  // ELU
    if (!LAST) {
        uint4 u;
        u.x = (unsigned)f2bf(o[0]) | ((unsigned)f2bf(o[1]) << 16);
        u.y = (unsigned)f2bf(o[2]) | ((unsigned)f2bf(o[3]) << 16);
        u.z = (unsigned)f2bf(o[4]) | ((unsigned)f2bf(o[5]) << 16);
        u.w = (unsigned)f2bf(o[6]) | ((unsigned)f2bf(o[7]) << 16);
        *(uint4*)(out16 + (size_t)node * HC + c0) = u;
    } else {
        float4 wA = *(const float4*)(lin_w + c0);
        float4 wB = *(const float4*)(lin_w + c0 + 4);
        float p = o[0] * wA.x + o[1] * wA.y + o[2] * wA.z + o[3] * wA.w +
                  o[4] * wB.x + o[5] * wB.y + o[6] * wB.z + o[7] * wB.w;
#pragma unroll
        for (int off = 1; off <= 16; off <<= 1) p += __shfl_xor(p, off, 64);  // within half
        if (l32 == 0) {
            int g = IDX(batch, node, mode[0]);
            atomicAdd(&gsum[g], p);
            atomicAdd(&gcnt[g], 1.f);
        }
    }
}

__global__ void final_kernel(const float* __restrict__ gsum, const float* __restrict__ gcnt,
                             const float* __restrict__ lin_b, float* __restrict__ outp) {
    int g = blockIdx.x * blockDim.x + threadIdx.x;
    if (g >= GRAPHS) return;
    float c = gcnt[g];
    c = c > 1.f ? c : 1.f;
    outp[g] = gsum[g] / c + lin_b[0];
}

// ------------------------------------------------------------------
extern "C" void kernel_launch(void* const* d_in, const int* in_sizes, int n_in,
                              void* d_out, int out_size, void* d_ws, size_t ws_size,
                              hipStream_t stream) {
    const float* x = (const float*)d_in[0];
    const void* edge = d_in[1];
    const void* batch = d_in[2];
    const float* W[3]    = {(const float*)d_in[3], (const float*)d_in[7],  (const float*)d_in[11]};
    const float* ASRC[3] = {(const float*)d_in[4], (const float*)d_in[8],  (const float*)d_in[12]};
    const float* ADST[3] = {(const float*)d_in[5], (const float*)d_in[9],  (const float*)d_in[13]};
    const float* BIAS[3] = {(const float*)d_in[6], (const float*)d_in[10], (const float*)d_in[14]};
    const float* lin_w = (const float*)d_in[15];
    const float* lin_b = (const float*)d_in[16];
    float* outp = (float*)d_out;

    const int n = in_sizes[0] / 128;  // 50000
    const int e = in_sizes[1] / 2;    // 800000
    const int IN_CH = 128;

    char* ws = (char*)d_ws;
    size_t off = 0;
    auto alloc = [&](size_t bytes) -> void* {
        void* p = ws + off;
        off = (off + bytes + 255) & ~(size_t)255;
        return p;
    };
    unsigned short* xb   = (unsigned short*)alloc((size_t)n * IN_CH * 2);
    unsigned short* hb16 = (unsigned short*)alloc((size_t)n * HC * 2);
    unsigned short* gb16 = (unsigned short*)alloc((size_t)n * HC * 2);
    unsigned short* wt0  = (unsigned short*)alloc((size_t)256 * IN_CH * 2);
    unsigned short* wt1  = (unsigned short*)alloc((size_t)256 * HC * 2);
    unsigned short* wt2  = (unsigned short*)alloc((size_t)256 * HC * 2);
    float* as_buf = (float*)alloc((size_t)n * HEADS * 4);
    float* ad_buf = (float*)alloc((size_t)n * HEADS * 4);
    int* hist     = (int*)alloc((size_t)n * 4);          // reused as fill
    int* row_ptr  = (int*)alloc((size_t)(n + 1) * 4);
    int* bsum     = (int*)alloc(1024);
    int* mode     = (int*)alloc(256);
    int* dhist    = (int*)alloc(1024);
    int* dfill    = (int*)alloc(1024);
    int* nodeperm = (int*)alloc((size_t)n * 4);
    int* srcs     = (int*)alloc((size_t)e * 4);
    int* dsts     = (int*)alloc((size_t)e * 4);
    unsigned short* wexp = (unsigned short*)alloc((size_t)e * HEADS * 2);
    float* gsum   = (float*)alloc((size_t)GRAPHS * 4);
    float* gcnt   = (float*)alloc((size_t)GRAPHS * 4);
    if (off > ws_size) return;

    const unsigned short* WT[3] = {wt0, wt1, wt2};
    const int nb = (n + 255) / 256;

    detect_kernel<<<1, 256, 0, stream>>>((const unsigned int*)edge, mode, e);

    // CSR build
    hipMemsetAsync(hist, 0, (size_t)n * 4, stream);
    hist_kernel<<<(e + 255) / 256, 256, 0, stream>>>(edge, mode, hist, e);
    scan1<<<nb, 256, 0, stream>>>(hist, row_ptr, bsum, n);
    scan2<<<1, 256, 0, stream>>>(bsum, nb);
    scan3<<<nb, 256, 0, stream>>>(row_ptr, bsum, n, e);
    hipMemsetAsync(hist, 0, (size_t)n * 4, stream);
    scatter_kernel<<<(e + 255) / 256, 256, 0, stream>>>(edge, mode, row_ptr, hist, srcs, dsts, e);

    // degree bucket-sort of nodes (once)
    hipMemsetAsync(dhist, 0, 1024, stream);
    hipMemsetAsync(dfill, 0, 1024, stream);
    deghist_kernel<<<nb, 256, 0, stream>>>(row_ptr, dhist, n);
    dscan_kernel<<<1, 256, 0, stream>>>(dhist);
    degscatter_kernel<<<nb, 256, 0, stream>>>(row_ptr, dhist, dfill, nodeperm, n);

    // casts / transposes
    cast_kernel<<<(n * IN_CH / 4 + 255) / 256, 256, 0, stream>>>(x, xb, n * IN_CH / 4);
    wtrans_kernel<<<(256 * IN_CH + 255) / 256, 256, 0, stream>>>(W[0], wt0, IN_CH);
    wtrans_kernel<<<(256 * HC + 255) / 256, 256, 0, stream>>>(W[1], wt1, HC);
    wtrans_kernel<<<(256 * HC + 255) / 256, 256, 0, stream>>>(W[2], wt2, HC);

    hipMemsetAsync(gsum, 0, (size_t)GRAPHS * 4, stream);
    hipMemsetAsync(gcnt, 0, (size_t)GRAPHS * 4, stream);

    const unsigned short* Ain = xb;
    int K = IN_CH;
    const int agg_blocks = (n + 7) / 8;   // 2 nodes/wave, 4 waves/block
    dim3 gemm_grid((n + 63) / 64, 2);
    for (int l = 0; l < 3; ++l) {
        gemm_mfma<<<gemm_grid, 256, 0, stream>>>(Ain, WT[l], hb16, ASRC[l], ADST[l],
                                                 as_buf, ad_buf, n, K);
        wexp_kernel<<<(e + 255) / 256, 256, 0, stream>>>(srcs, dsts, as_buf, ad_buf, wexp, e);
        if (l < 2) {
            gat_aggregate<false><<<agg_blocks, 256, 0, stream>>>(
                hb16, wexp, as_buf, ad_buf, row_ptr, srcs, nodeperm, BIAS[l], gb16,
                batch, mode, lin_w, gsum, gcnt, n);
        } else {
            gat_aggregate<true><<<agg_blocks, 256, 0, stream>>>(
                hb16, wexp, as_buf, ad_buf, row_ptr, srcs, nodeperm, BIAS[l], nullptr,
                batch, mode, lin_w, gsum, gcnt, n);
        }
        Ain = gb16;
        K = HC;
    }

    final_kernel<<<2, 256, 0, stream>>>(gsum, gcnt, lin_b, outp);
}

// Round 14
// 465.547 us; speedup vs baseline: 1.4791x; 1.4791x over previous
//
#include <hip/hip_runtime.h>

#define HC 256      // HEADS*HID
#define HEADS 8
#define HID 32
#define GRAPHS 512
#define NEG_SLOPE 0.2f

typedef __bf16 bf16x8 __attribute__((ext_vector_type(8)));
typedef float f32x4 __attribute__((ext_vector_type(4)));

// ------------------------------------------------------------------
// bf16 helpers (round-to-nearest-even)
__device__ __forceinline__ unsigned short f2bf(float x) {
    unsigned u = __float_as_uint(x);
    return (unsigned short)((u + 0x7fffu + ((u >> 16) & 1u)) >> 16);
}
__device__ __forceinline__ float bf2f(unsigned short b) {
    return __uint_as_float(((unsigned)b) << 16);
}

// int32/int64 index handling (JAX may emit either for edge_index/batch)
__device__ __forceinline__ int IDX(const void* p, long long i, int mode) {
    if (mode) return (int)((const long long*)p)[i];
    return ((const int*)p)[i];
}

__global__ void detect_kernel(const unsigned int* __restrict__ words, int* __restrict__ mode, int e) {
    __shared__ unsigned int red[256];
    unsigned int v = 0;
    int lim = e < 4096 ? e : 4096;
    for (int i = threadIdx.x; i < lim; i += 256) v |= words[2 * i + 1];
    red[threadIdx.x] = v;
    __syncthreads();
    for (int off = 128; off > 0; off >>= 1) {
        if (threadIdx.x < off) red[threadIdx.x] |= red[threadIdx.x + off];
        __syncthreads();
    }
    if (threadIdx.x == 0) *mode = (red[0] == 0u) ? 1 : 0;  // 1 => int64
}

// ------------------------------------------------------------------
// CSR build: histogram -> scan -> scatter
__global__ void hist_kernel(const void* __restrict__ edge, const int* __restrict__ mode,
                            int* __restrict__ hist, int e) {
    int m = mode[0];
    int i = blockIdx.x * blockDim.x + threadIdx.x;
    if (i < e) atomicAdd(&hist[IDX(edge, (long long)e + i, m)], 1);
}

__global__ void scan1(const int* __restrict__ hist, int* __restrict__ excl,
                      int* __restrict__ bsum, int n) {
    __shared__ int buf[256];
    int i = blockIdx.x * 256 + threadIdx.x;
    int v = (i < n) ? hist[i] : 0;
    buf[threadIdx.x] = v;
    __syncthreads();
    for (int off = 1; off < 256; off <<= 1) {
        int t = (threadIdx.x >= (unsigned)off) ? buf[threadIdx.x - off] : 0;
        __syncthreads();
        buf[threadIdx.x] += t;
        __syncthreads();
    }
    if (i < n) excl[i] = buf[threadIdx.x] - v;
    if (threadIdx.x == 255) bsum[blockIdx.x] = buf[255];
}

__global__ void scan2(int* __restrict__ bsum, int nb) {
    __shared__ int buf[256];
    int v = (threadIdx.x < (unsigned)nb) ? bsum[threadIdx.x] : 0;
    buf[threadIdx.x] = v;
    __syncthreads();
    for (int off = 1; off < 256; off <<= 1) {
        int t = (threadIdx.x >= (unsigned)off) ? buf[threadIdx.x - off] : 0;
        __syncthreads();
        buf[threadIdx.x] += t;
        __syncthreads();
    }
    if (threadIdx.x < (unsigned)nb) bsum[threadIdx.x] = buf[threadIdx.x] - v;  // exclusive
}

__global__ void scan3(int* __restrict__ row_ptr, const int* __restrict__ bsum, int n, int e) {
    int i = blockIdx.x * 256 + threadIdx.x;
    if (i < n) row_ptr[i] += bsum[i >> 8];
    if (i == 0) row_ptr[n] = e;
}

__global__ void scatter_kernel(const void* __restrict__ edge, const int* __restrict__ mode,
                               const int* __restrict__ row_ptr, int* __restrict__ fill,
                               int* __restrict__ outs, int* __restrict__ outd, int e) {
    int m = mode[0];
    int i = blockIdx.x * blockDim.x + threadIdx.x;
    if (i < e) {
        int d = IDX(edge, (long long)e + i, m);
        int pos = row_ptr[d] + atomicAdd(&fill[d], 1);
        outs[pos] = IDX(edge, (long long)i, m);
        outd[pos] = d;
    }
}

// ------------------------------------------------------------------
// x fp32 -> bf16 cast (vectorized)
__global__ void cast_kernel(const float* __restrict__ x, unsigned short* __restrict__ xb,
                            int nquad) {
    int i = blockIdx.x * blockDim.x + threadIdx.x;
    if (i >= nquad) return;
    float4 v = *(const float4*)(x + (size_t)i * 4);
    ushort4 u = {f2bf(v.x), f2bf(v.y), f2bf(v.z), f2bf(v.w)};
    *(ushort4*)(xb + (size_t)i * 4) = u;
}

// W fp32 [K][256] -> Wt bf16 [256][K]
__global__ void wtrans_kernel(const float* __restrict__ W, unsigned short* __restrict__ Wt,
                              int K) {
    int idx = blockIdx.x * blockDim.x + threadIdx.x;
    if (idx >= 256 * K) return;
    int c = idx / K, k = idx - c * K;
    Wt[idx] = f2bf(W[(size_t)k * 256 + c]);
}

// ------------------------------------------------------------------
// bf16 MFMA GEMM with FUSED alpha epilogue.
// Cb[M,256] = A[M,K] @ W[K,256]; also asrc/adst[row][head] = <h_row, a_vec>
// Block 64x128, 4 waves (2x2), each wave 32x64 = 2x4 fragments of 16x16x32.
// C/D layout (m89-verified): col = lane&15, row = (lane>>4)*4 + reg.
__global__ __launch_bounds__(256) void gemm_mfma(const unsigned short* __restrict__ A,
                                                 const unsigned short* __restrict__ Wt,
                                                 unsigned short* __restrict__ Cb,
                                                 const float* __restrict__ a_src,
                                                 const float* __restrict__ a_dst,
                                                 float* __restrict__ asrc,
                                                 float* __restrict__ adst,
                                                 int M, int K) {
    __shared__ unsigned short Ab[64][40];    // pad 40 shorts (80B): 16B-aligned, 2-way max
    __shared__ unsigned short Bt[128][40];
    const int tid = threadIdx.x;
    const int wave = tid >> 6, lane = tid & 63;
    const int wr = wave >> 1, wc = wave & 1;
    const int row0 = blockIdx.x * 64, col0 = blockIdx.y * 128;
    const int r4 = tid >> 2, q = tid & 3;
    const int l15 = lane & 15, g8 = (lane >> 4) * 8;
    f32x4 acc[2][4] = {};

    for (int k0 = 0; k0 < K; k0 += 32) {
        int ar = row0 + r4;
        ar = ar < M ? ar : M - 1;
        *(uint4*)&Ab[r4][q * 8] = *(const uint4*)&A[(size_t)ar * K + k0 + q * 8];
#pragma unroll
        for (int h = 0; h < 2; ++h) {
            int br = r4 + h * 64;
            *(uint4*)&Bt[br][q * 8] = *(const uint4*)&Wt[(size_t)(col0 + br) * K + k0 + q * 8];
        }
        __syncthreads();
        bf16x8 af[2], bfr[4];
#pragma unroll
        for (int i = 0; i < 2; ++i) af[i] = *(const bf16x8*)&Ab[wr * 32 + i * 16 + l15][g8];
#pragma unroll
        for (int j = 0; j < 4; ++j) bfr[j] = *(const bf16x8*)&Bt[wc * 64 + j * 16 + l15][g8];
#pragma unroll
        for (int i = 0; i < 2; ++i)
#pragma unroll
            for (int j = 0; j < 4; ++j)
                acc[i][j] = __builtin_amdgcn_mfma_f32_16x16x32_bf16(af[i], bfr[j], acc[i][j],
                                                                    0, 0, 0);
        __syncthreads();
    }
    const int g = lane >> 4;
    const int colbase = col0 + wc * 64;
    const int headA = colbase >> 5, headB = headA + 1;
    const float asA0 = a_src[headA * 32 + l15], asA1 = a_src[headA * 32 + 16 + l15];
    const float asB0 = a_src[headB * 32 + l15], asB1 = a_src[headB * 32 + 16 + l15];
    const float adA0 = a_dst[headA * 32 + l15], adA1 = a_dst[headA * 32 + 16 + l15];
    const float adB0 = a_dst[headB * 32 + l15], adB1 = a_dst[headB * 32 + 16 + l15];
#pragma unroll
    for (int i = 0; i < 2; ++i) {
#pragma unroll
        for (int r = 0; r < 4; ++r) {
            int row = row0 + wr * 32 + i * 16 + g * 4 + r;
            float pa = acc[i][0][r] * asA0 + acc[i][1][r] * asA1;
            float pb = acc[i][2][r] * asB0 + acc[i][3][r] * asB1;
            float qa = acc[i][0][r] * adA0 + acc[i][1][r] * adA1;
            float qb = acc[i][2][r] * adB0 + acc[i][3][r] * adB1;
#pragma unroll
            for (int off = 1; off < 16; off <<= 1) {
                pa += __shfl_xor(pa, off, 64);
                pb += __shfl_xor(pb, off, 64);
                qa += __shfl_xor(qa, off, 64);
                qb += __shfl_xor(qb, off, 64);
            }
            if (row < M) {
                if (l15 == 0) {
                    asrc[row * 8 + headA] = pa;
                    asrc[row * 8 + headB] = pb;
                    adst[row * 8 + headA] = qa;
                    adst[row * 8 + headB] = qb;
                }
#pragma unroll
                for (int j = 0; j < 4; ++j) {
                    int col = colbase + j * 16 + l15;
                    Cb[(size_t)row * HC + col] = f2bf(acc[i][j][r]);
                }
            }
        }
    }
}

// ------------------------------------------------------------------
// per-edge exponentiated weights (no max-shift), CSR order, layout [E][8] bf16
__global__ void wexp_kernel(const int* __restrict__ srcs, const int* __restrict__ dsts,
                            const float* __restrict__ asrc, const float* __restrict__ adst,
                            unsigned short* __restrict__ wexp, int e) {
    int i = blockIdx.x * blockDim.x + threadIdx.x;
    if (i >= e) return;
    int s = srcs[i], d = dsts[i];
    float4 s0 = *(const float4*)(asrc + (size_t)s * 8);
    float4 s1 = *(const float4*)(asrc + (size_t)s * 8 + 4);
    float4 d0 = *(const float4*)(adst + (size_t)d * 8);
    float4 d1 = *(const float4*)(adst + (size_t)d * 8 + 4);
    float v[8] = {s0.x + d0.x, s0.y + d0.y, s0.z + d0.z, s0.w + d0.w,
                  s1.x + d1.x, s1.y + d1.y, s1.z + d1.z, s1.w + d1.w};
    ushort4 u0, u1;
#pragma unroll
    for (int q = 0; q < 8; ++q) {
        float t = v[q] > 0.f ? v[q] : NEG_SLOPE * v[q];
        v[q] = __expf(fminf(t, 75.f));
    }
    u0 = (ushort4){f2bf(v[0]), f2bf(v[1]), f2bf(v[2]), f2bf(v[3])};
    u1 = (ushort4){f2bf(v[4]), f2bf(v[5]), f2bf(v[6]), f2bf(v[7])};
    *(ushort4*)(wexp + (size_t)i * 8) = u0;
    *(ushort4*)(wexp + (size_t)i * 8 + 4) = u1;
}

// ------------------------------------------------------------------
// SINGLE-PASS aggregate: stream precomputed bf16 wexp + gather rows (chain depth 1).
// TWO nodes per wave (one per 32-lane half); lane owns 8 channels (uint4 row).
// !LAST writes bf16 output (feeds next layer's MFMA GEMM directly).
#define ACC_EDGE(gv, wv)                                                      \
    do {                                                                      \
        unsigned _u0 = gv.x, _u1 = gv.y, _u2 = gv.z, _u3 = gv.w;              \
        acc[0] = fmaf(wv, __uint_as_float(_u0 << 16), acc[0]);                \
        acc[1] = fmaf(wv, __uint_as_float(_u0 & 0xffff0000u), acc[1]);        \
        acc[2] = fmaf(wv, __uint_as_float(_u1 << 16), acc[2]);                \
        acc[3] = fmaf(wv, __uint_as_float(_u1 & 0xffff0000u), acc[3]);        \
        acc[4] = fmaf(wv, __uint_as_float(_u2 << 16), acc[4]);                \
        acc[5] = fmaf(wv, __uint_as_float(_u2 & 0xffff0000u), acc[5]);        \
        acc[6] = fmaf(wv, __uint_as_float(_u3 << 16), acc[6]);                \
        acc[7] = fmaf(wv, __uint_as_float(_u3 & 0xffff0000u), acc[7]);        \
    } while (0)

template <bool LAST>
__global__ __launch_bounds__(256) void gat_aggregate(
    const unsigned short* __restrict__ hb, const unsigned short* __restrict__ wexp,
    const float* __restrict__ asrc, const float* __restrict__ adst,
    const int* __restrict__ row_ptr, const int* __restrict__ srcs,
    const float* __restrict__ bias, unsigned short* __restrict__ out16,
    const void* __restrict__ batch, const int* __restrict__ mode,
    const float* __restrict__ lin_w, float* __restrict__ gsum,
    float* __restrict__ gcnt, int n) {
    const int lane = threadIdx.x & 63;
    const int half = lane >> 5;
    const int l32 = lane & 31;
    int wid = (int)((blockIdx.x * blockDim.x + threadIdx.x) >> 6);
    int node = wid * 2 + half;
    if (node >= n) return;
    const int head = l32 >> 2;
    const int c0 = l32 * 8;
    const int beg = row_ptr[node], end = row_ptr[node + 1];

    // self-loop weight (fp32, exact)
    float e0 = asrc[node * 8 + head] + adst[node * 8 + head];
    e0 = e0 > 0.f ? e0 : NEG_SLOPE * e0;
    float w0 = __expf(fminf(e0, 75.f));
    float denom = w0;
    float acc[8] = {};
    {
        uint4 g = *(const uint4*)(hb + (size_t)node * HC + c0);
        ACC_EDGE(g, w0);
    }
    int j = beg;
    for (; j + 4 <= end; j += 4) {
        int s0 = srcs[j], s1 = srcs[j + 1], s2 = srcs[j + 2], s3 = srcs[j + 3];
        uint4 g0 = *(const uint4*)(hb + (size_t)s0 * HC + c0);
        uint4 g1 = *(const uint4*)(hb + (size_t)s1 * HC + c0);
        uint4 g2 = *(const uint4*)(hb + (size_t)s2 * HC + c0);
        uint4 g3 = *(const uint4*)(hb + (size_t)s3 * HC + c0);
        float x0 = bf2f(wexp[(size_t)(j + 0) * 8 + head]);
        float x1 = bf2f(wexp[(size_t)(j + 1) * 8 + head]);
        float x2 = bf2f(wexp[(size_t)(j + 2) * 8 + head]);
        float x3 = bf2f(wexp[(size_t)(j + 3) * 8 + head]);
        denom += x0 + x1 + x2 + x3;
        ACC_EDGE(g0, x0);
        ACC_EDGE(g1, x1);
        ACC_EDGE(g2, x2);
        ACC_EDGE(g3, x3);
    }
    for (; j < end; ++j) {
        int s = srcs[j];
        uint4 g = *(const uint4*)(hb + (size_t)s * HC + c0);
        float x = bf2f(wexp[(size_t)j * 8 + head]);
        denom += x;
        ACC_EDGE(g, x);
    }

    const float invd = 1.f / (denom + 1e-16f);
    float4 b0 = *(const float4*)(bias + c0);
    float4 b1 = *(const float4*)(bias + c0 + 4);
    float o[8] = {fmaf(acc[0], invd, b0.x), fmaf(acc[1], invd, b0.y),
                  fmaf(acc[2], invd, b0.z), fmaf(acc[3], invd, b0.w),
                  fmaf(acc[4], invd, b1.x), fmaf(acc[5], invd, b1.y),
                  fmaf(acc[6], invd, b1.z), fmaf(acc[7], invd, b1.w)};
#pragma unroll
    for (int q = 0; q < 8; ++q) o[q] = o[q] > 0.f ? o[q] : __expf(o[q]) - 1.f;  // ELU
    if (!LAST) {
        uint4 u;
        u.x = (unsigned)f2bf(o[0]) | ((unsigned)f2bf(o[1]) << 16);
        u.y = (unsigned)f2bf(o[2]) | ((unsigned)f2bf(o[3]) << 16);
        u.z = (unsigned)f2bf(o[4]) | ((unsigned)f2bf(o[5]) << 16);
        u.w = (unsigned)f2bf(o[6]) | ((unsigned)f2bf(o[7]) << 16);
        *(uint4*)(out16 + (size_t)node * HC + c0) = u;
    } else {
        float4 wA = *(const float4*)(lin_w + c0);
        float4 wB = *(const float4*)(lin_w + c0 + 4);
        float p = o[0] * wA.x + o[1] * wA.y + o[2] * wA.z + o[3] * wA.w +
                  o[4] * wB.x + o[5] * wB.y + o[6] * wB.z + o[7] * wB.w;
#pragma unroll
        for (int off = 1; off <= 16; off <<= 1) p += __shfl_xor(p, off, 64);  // within half
        if (l32 == 0) {
            int g = IDX(batch, node, mode[0]);
            atomicAdd(&gsum[g], p);
            atomicAdd(&gcnt[g], 1.f);
        }
    }
}

__global__ void final_kernel(const float* __restrict__ gsum, const float* __restrict__ gcnt,
                             const float* __restrict__ lin_b, float* __restrict__ outp) {
    int g = blockIdx.x * blockDim.x + threadIdx.x;
    if (g >= GRAPHS) return;
    float c = gcnt[g];
    c = c > 1.f ? c : 1.f;
    outp[g] = gsum[g] / c + lin_b[0];
}

// ------------------------------------------------------------------
extern "C" void kernel_launch(void* const* d_in, const int* in_sizes, int n_in,
                              void* d_out, int out_size, void* d_ws, size_t ws_size,
                              hipStream_t stream) {
    const float* x = (const float*)d_in[0];
    const void* edge = d_in[1];
    const void* batch = d_in[2];
    const float* W[3]    = {(const float*)d_in[3], (const float*)d_in[7],  (const float*)d_in[11]};
    const float* ASRC[3] = {(const float*)d_in[4], (const float*)d_in[8],  (const float*)d_in[12]};
    const float* ADST[3] = {(const float*)d_in[5], (const float*)d_in[9],  (const float*)d_in[13]};
    const float* BIAS[3] = {(const float*)d_in[6], (const float*)d_in[10], (const float*)d_in[14]};
    const float* lin_w = (const float*)d_in[15];
    const float* lin_b = (const float*)d_in[16];
    float* outp = (float*)d_out;

    const int n = in_sizes[0] / 128;  // 50000
    const int e = in_sizes[1] / 2;    // 800000
    const int IN_CH = 128;

    char* ws = (char*)d_ws;
    size_t off = 0;
    auto alloc = [&](size_t bytes) -> void* {
        void* p = ws + off;
        off = (off + bytes + 255) & ~(size_t)255;
        return p;
    };
    unsigned short* xb   = (unsigned short*)alloc((size_t)n * IN_CH * 2);
    unsigned short* hb16 = (unsigned short*)alloc((size_t)n * HC * 2);
    unsigned short* gb16 = (unsigned short*)alloc((size_t)n * HC * 2);
    unsigned short* wt0  = (unsigned short*)alloc((size_t)256 * IN_CH * 2);
    unsigned short* wt1  = (unsigned short*)alloc((size_t)256 * HC * 2);
    unsigned short* wt2  = (unsigned short*)alloc((size_t)256 * HC * 2);
    float* as_buf = (float*)alloc((size_t)n * HEADS * 4);
    float* ad_buf = (float*)alloc((size_t)n * HEADS * 4);
    int* hist     = (int*)alloc((size_t)n * 4);          // reused as fill
    int* row_ptr  = (int*)alloc((size_t)(n + 1) * 4);
    int* bsum     = (int*)alloc(1024);
    int* mode     = (int*)alloc(256);
    int* srcs     = (int*)alloc((size_t)e * 4);
    int* dsts     = (int*)alloc((size_t)e * 4);
    unsigned short* wexp = (unsigned short*)alloc((size_t)e * HEADS * 2);
    float* gsum   = (float*)alloc((size_t)GRAPHS * 4);
    float* gcnt   = (float*)alloc((size_t)GRAPHS * 4);
    if (off > ws_size) return;

    const unsigned short* WT[3] = {wt0, wt1, wt2};
    const int nb = (n + 255) / 256;

    detect_kernel<<<1, 256, 0, stream>>>((const unsigned int*)edge, mode, e);

    // CSR build
    hipMemsetAsync(hist, 0, (size_t)n * 4, stream);
    hist_kernel<<<(e + 255) / 256, 256, 0, stream>>>(edge, mode, hist, e);
    scan1<<<nb, 256, 0, stream>>>(hist, row_ptr, bsum, n);
    scan2<<<1, 256, 0, stream>>>(bsum, nb);
    scan3<<<nb, 256, 0, stream>>>(row_ptr, bsum, n, e);
    hipMemsetAsync(hist, 0, (size_t)n * 4, stream);
    scatter_kernel<<<(e + 255) / 256, 256, 0, stream>>>(edge, mode, row_ptr, hist, srcs, dsts, e);

    // casts / transposes
    cast_kernel<<<(n * IN_CH / 4 + 255) / 256, 256, 0, stream>>>(x, xb, n * IN_CH / 4);
    wtrans_kernel<<<(256 * IN_CH + 255) / 256, 256, 0, stream>>>(W[0], wt0, IN_CH);
    wtrans_kernel<<<(256 * HC + 255) / 256, 256, 0, stream>>>(W[1], wt1, HC);
    wtrans_kernel<<<(256 * HC + 255) / 256, 256, 0, stream>>>(W[2], wt2, HC);

    hipMemsetAsync(gsum, 0, (size_t)GRAPHS * 4, stream);
    hipMemsetAsync(gcnt, 0, (size_t)GRAPHS * 4, stream);

    const unsigned short* Ain = xb;
    int K = IN_CH;
    const int agg_blocks = (n + 7) / 8;   // 2 nodes/wave, 4 waves/block
    dim3 gemm_grid((n + 63) / 64, 2);
    for (int l = 0; l < 3; ++l) {
        gemm_mfma<<<gemm_grid, 256, 0, stream>>>(Ain, WT[l], hb16, ASRC[l], ADST[l],
                                                 as_buf, ad_buf, n, K);
        wexp_kernel<<<(e + 255) / 256, 256, 0, stream>>>(srcs, dsts, as_buf, ad_buf, wexp, e);
        if (l < 2) {
            gat_aggregate<false><<<agg_blocks, 256, 0, stream>>>(
                hb16, wexp, as_buf, ad_buf, row_ptr, srcs, BIAS[l], gb16,
                batch, mode, lin_w, gsum, gcnt, n);
        } else {
            gat_aggregate<true><<<agg_blocks, 256, 0, stream>>>(
                hb16, wexp, as_buf, ad_buf, row_ptr, srcs, BIAS[l], nullptr,
                batch, mode, lin_w, gsum, gcnt, n);
        }
        Ain = gb16;
        K = HC;
    }

    final_kernel<<<2, 256, 0, stream>>>(gsum, gcnt, lin_b, outp);
}